// Round 4
// baseline (205.425 us; speedup 1.0000x reference)
//
#include <hip/hip_runtime.h>
#include <hip/hip_bf16.h>
#include <math.h>

#define B_   4
#define T_   4096
#define DIN_ 1024
#define H_   16
#define D_   64
#define M_   (B_*T_)      // 16384
#define N_   (H_*D_*2)    // 2048
#define K_   DIN_         // 1024
#define C_   64           // scan chunks per (b,h) chain
#define CL_  (T_/C_)      // 64 steps per chunk

typedef unsigned short u16;
typedef __attribute__((ext_vector_type(8))) short short8_t;
typedef __attribute__((ext_vector_type(4))) float float4_t;

__device__ __forceinline__ u16 f2bf(float f) {
  unsigned int x = __float_as_uint(f);
  x += 0x7fffu + ((x >> 16) & 1u);   // round-to-nearest-even (finite inputs)
  return (u16)(x >> 16);
}
__device__ __forceinline__ float bf2f(unsigned int u) {
  return __uint_as_float((u & 0xffffu) << 16);
}
__device__ __forceinline__ unsigned pk_bf16(float x, float y) {
  float2 f; f.x = x; f.y = y;
  union { __hip_bfloat162 h2; unsigned u; } c;
  c.h2 = __float22bfloat162_rn(f);
  return c.u;
}

// async global->LDS, 16 B per lane. LDS dest = wave-uniform base + lane*16.
__device__ __forceinline__ void g2l16(const u16* g, u16* l) {
  __builtin_amdgcn_global_load_lds(
      (const __attribute__((address_space(1))) void*)g,
      (__attribute__((address_space(3))) void*)l, 16, 0, 0);
}

// ---------------- prep: cast inputs + cast-transpose weights (unchanged) ----------------
__global__ __launch_bounds__(256)
void prep(const float* __restrict__ inputs, const float* __restrict__ kvk,
          u16* __restrict__ aB, u16* __restrict__ wBt) {
  __shared__ float tile[32][33];
  int bid = blockIdx.x;
  int tid = threadIdx.x;
  if (bid < 8192) {
    int i = bid * 256 + tid;          // over M*K/8
    const float4* src = (const float4*)inputs;
    float4 a = src[2*i], b = src[2*i+1];
    uint4 o;
    o.x = pk_bf16(a.x, a.y);
    o.y = pk_bf16(a.z, a.w);
    o.z = pk_bf16(b.x, b.y);
    o.w = pk_bf16(b.z, b.w);
    ((uint4*)aB)[i] = o;
  } else {
    int b2 = bid - 8192;              // 2048 blocks
    int kb = (b2 & 31) * 32;          // K/32 = 32
    int nb = (b2 >> 5) * 32;          // N/32 = 64
    int r  = tid >> 3;                // 0..31
    int c4 = (tid & 7) * 4;           // 0..28
    float4 v = *(const float4*)&kvk[(size_t)(kb + r) * N_ + nb + c4];
    tile[r][c4+0] = v.x; tile[r][c4+1] = v.y; tile[r][c4+2] = v.z; tile[r][c4+3] = v.w;
    __syncthreads();
    uint2 o;
    o.x = pk_bf16(tile[c4+0][r], tile[c4+1][r]);
    o.y = pk_bf16(tile[c4+2][r], tile[c4+3][r]);
    *(uint2*)&wBt[(size_t)(nb + r) * K_ + kb + c4] = o;
  }
}

// ---------------- gemm_kv: 256x256 tile, 8-phase counted-vmcnt K-loop (R2-identical) ----
// R4 epilogue: vtile back to t-major [t][72] (R3's [d][t] layout was an
// unavoidable >=8-way bank conflict: any 16B-aligned row stride is ==0 mod 4
// dwords -> d-strided access hits only banks {0,4,..,28}).
// pass1 W is now computed FROM THE ACC REGISTERS (no LDS v re-read); U via
// shuffle-reduce in the p-phase. Deletes the 64-iter pass1 LDS loop + 1 barrier.

#define FENCE asm volatile("" ::: "memory")
#define KBAR do { FENCE; __builtin_amdgcn_s_barrier(); FENCE; } while (0)

#define STAGE_A(P, KT, CC) do { \
  g2l16(gA + ((size_t)((CC)*64      ) * K_ + (KT)*64), lds + (P)*16384 +        (CC)*4096 + wv*512); \
  g2l16(gA + ((size_t)((CC)*64 + 128) * K_ + (KT)*64), lds + (P)*16384 + 8192 + (CC)*4096 + wv*512); \
} while (0)

#define STAGE_B(P, KT, HH) do { \
  g2l16(gB + ((size_t)((HH)*128     ) * K_ + (KT)*64), lds + 32768 + (P)*16384 + (HH)*8192 +        wv*512); \
  g2l16(gB + ((size_t)((HH)*128 + 64) * K_ + (KT)*64), lds + 32768 + (P)*16384 + (HH)*8192 + 4096 + wv*512); \
} while (0)

#define READ_A(P, MH) do { _Pragma("unroll") \
  for (int il_ = 0; il_ < 4; ++il_) { \
    const int o_ = (P)*16384 + aBase + (MH)*4096 + il_*1024; \
    af[il_][0] = *(const short8_t*)&lds[o_ + s0]; \
    af[il_][1] = *(const short8_t*)&lds[o_ + s1]; \
  } } while (0)

#define READ_B(P, NH) do { _Pragma("unroll") \
  for (int jl_ = 0; jl_ < 2; ++jl_) { \
    const int o_ = (P)*16384 + (NH)*8192 + bBase + jl_*1024; \
    bfr[NH][jl_][0] = *(const short8_t*)&lds[o_ + s0]; \
    bfr[NH][jl_][1] = *(const short8_t*)&lds[o_ + s1]; \
  } } while (0)

#define MFMA_Q(MH, NH) do { \
  __builtin_amdgcn_s_setprio(1); \
  _Pragma("unroll") for (int kk_ = 0; kk_ < 2; ++kk_) \
  _Pragma("unroll") for (int il_ = 0; il_ < 4; ++il_) \
  _Pragma("unroll") for (int jl_ = 0; jl_ < 2; ++jl_) \
    acc[(MH)*4+il_][(NH)*2+jl_] = __builtin_amdgcn_mfma_f32_16x16x32_bf16( \
        af[il_][kk_], bfr[NH][jl_][kk_], acc[(MH)*4+il_][(NH)*2+jl_], 0, 0, 0); \
  __builtin_amdgcn_s_setprio(0); \
} while (0)

__global__ __launch_bounds__(512, 2)
void gemm_kv(const u16* __restrict__ A, const u16* __restrict__ Bt,
             const float* __restrict__ q,
             float* __restrict__ pbuf, u16* __restrict__ vbuf,
             float* __restrict__ aggU, float* __restrict__ aggW) {
  extern __shared__ __align__(16) char smem[];
  u16* lds = (u16*)smem;

  const int tid  = threadIdx.x;
  const int wv   = tid >> 6;
  const int lane = tid & 63;
  const int quad = lane >> 4;
  const int l16  = lane & 15;
  const int wr   = wv >> 2;           // 0..1  (m: 128-row half)
  const int wc   = wv & 3;            // 0..3  (n: 32 cols of each head)

  // XCD-aware bijective swizzle (512 % 8 == 0); same-XCD blocks share mt range.
  const int g  = blockIdx.x;
  const int wg = (g & 7) * 64 + (g >> 3);
  const int nt = wg & 7;              // 0..7  -> heads {2nt, 2nt+1}
  const int mt = wg >> 3;             // 0..63 -> rows [mt*256, +256)
  const int bm = mt * 256;
  const int bn = nt * 256;

  // staging decomposition: thread -> (row-in-call, 16B granule), src pre-XOR'd
  const int tr   = tid >> 3;          // 0..63
  const int gran = tid & 7;
  const u16* gA = A  + (size_t)(bm + tr) * K_ + ((gran ^ (tr & 7)) * 8);
  const u16* gB = Bt + (size_t)(bn + tr) * K_ + ((gran ^ (tr & 7)) * 8);

  // fragment ds_read bases (u16 units); XOR matches staged layout
  const int s0 = ((quad    ) ^ (l16 & 7)) * 8;
  const int s1 = ((quad + 4) ^ (l16 & 7)) * 8;
  const int aBase = wr * 8192 + l16 * 64;           // + P*16384 + MH*4096 + il*1024
  const int bBase = 32768 + wc * 2048 + l16 * 64;   // + P*16384 + NH*8192 + jl*1024

  float4_t acc[8][4] = {};
  short8_t af[4][2];
  short8_t bfr[2][2][2];

  // prologue: kt0 full (8 loads) + kt1 A.c0/B.h0 (4 loads); keep kt1's 4 in flight
  STAGE_A(0, 0, 0); STAGE_A(0, 0, 1);
  STAGE_B(0, 0, 0); STAGE_B(0, 0, 1);
  STAGE_A(1, 1, 0); STAGE_B(1, 1, 0);
  asm volatile("s_waitcnt vmcnt(4)" ::: "memory");
  KBAR;

#pragma unroll 1
  for (int it = 0; it < 8; ++it) {
    const int kt1 = 2*it + 1, kt2 = 2*it + 2, kt3 = 2*it + 3;
    const bool more = (it < 7);
    // ph0
    READ_A(0, 0); READ_B(0, 0);
    STAGE_A(1, kt1, 1);
    KBAR;
    MFMA_Q(0, 0);
    KBAR;
    // ph1
    READ_B(0, 1);
    STAGE_B(1, kt1, 1);
    KBAR;
    MFMA_Q(0, 1);
    KBAR;
    // ph2
    READ_A(0, 1);
    if (more) STAGE_A(0, kt2, 0);
    KBAR;
    MFMA_Q(1, 0);
    KBAR;
    // ph3 (+ parity checkpoint)
    if (more) STAGE_B(0, kt2, 0);
    KBAR;
    MFMA_Q(1, 1);
    if (more) asm volatile("s_waitcnt vmcnt(4)" ::: "memory");
    else      asm volatile("s_waitcnt vmcnt(0)" ::: "memory");
    KBAR;
    // ph4
    READ_A(1, 0); READ_B(1, 0);
    if (more) STAGE_A(0, kt2, 1);
    KBAR;
    MFMA_Q(0, 0);
    KBAR;
    // ph5
    READ_B(1, 1);
    if (more) STAGE_B(0, kt2, 1);
    KBAR;
    MFMA_Q(0, 1);
    KBAR;
    // ph6
    READ_A(1, 1);
    if (more) STAGE_A(1, kt3, 0);
    KBAR;
    MFMA_Q(1, 0);
    KBAR;
    // ph7 (+ parity checkpoint)
    if (more) STAGE_B(1, kt3, 0);
    KBAR;
    MFMA_Q(1, 1);
    if (more) asm volatile("s_waitcnt vmcnt(4)" ::: "memory");
    KBAR;
  }

  // ---------------- fused epilogue (R4) ----------------
  // C/D frag layout: col(n) = l16, row(m) = quad*4 + reg.
  // t = wr*128 + i*16 + quad*4 + r;  head = nh;  n' = wc*32 + jl*16 + l16.
  // odd n' (odd l16) -> v column d = wc*16 + jl*8 + (l16>>1); even -> k column.
  u16*   vtile = (u16*)smem;                  // [2][256][72] u16  = 73728 B
  float* sred  = (float*)(smem + 73728);      // [2][256][17] f32  = 34816 B
  float* pS    = (float*)(smem + 108544);     // [2][256]     f32  =  2048 B

  float qv[2][2];
#pragma unroll
  for (int nh = 0; nh < 2; ++nh)
#pragma unroll
    for (int jl = 0; jl < 2; ++jl)
      qv[nh][jl] = q[nt*128 + nh*64 + wc*16 + jl*8 + (l16 >> 1)];

#pragma unroll
  for (int nh = 0; nh < 2; ++nh) {
#pragma unroll
    for (int i = 0; i < 8; ++i) {
#pragma unroll
      for (int r = 0; r < 4; ++r) {
        const int t = wr*128 + i*16 + quad*4 + r;
        const float x0 = fmaxf(acc[i][nh*2+0][r], 0.f);
        const float x1 = fmaxf(acc[i][nh*2+1][r], 0.f);
        if (l16 & 1) {             // v columns -> staged transpose
          const int d0 = (wc*32 + l16) >> 1;
          vtile[(nh*256 + t)*72 + d0    ] = f2bf(x0);
          vtile[(nh*256 + t)*72 + d0 + 8] = f2bf(x1);
        }
        float ps = qv[nh][0]*x0 + qv[nh][1]*x1;   // valid on even lanes
        ps += __shfl_xor(ps, 2);
        if ((l16 & 3) == 0)
          sred[(nh*256 + t)*17 + wc*4 + (l16 >> 2)] = ps;
      }
    }
  }
  __syncthreads();

  const int b  = mt >> 4;             // 16 m-tiles per batch
  const int t0 = (mt & 15) * 256;
  {
    // p-phase: s reduction -> p = exp(clamp(s)); wave = one (hh, chunk) -> U shfl-reduce
    const int hh = tid >> 8;          // head-local 0/1
    const int t  = tid & 255;
    float s = 0.f;
#pragma unroll
    for (int k = 0; k < 16; ++k) s += sred[(hh*256 + t)*17 + k];
    float p = __expf(fminf(fmaxf(s, -60.f), 60.f));
    pS[hh*256 + t] = p;
    pbuf[(size_t)(b*H_ + nt*2 + hh) * T_ + t0 + t] = p;
    float u = p;
#pragma unroll
    for (int off = 32; off; off >>= 1) u += __shfl_down(u, off);
    if (lane == 0) {
      const int ch = (tid >> 6) & 3;  // chunk within this head's 256 t
      aggU[(b*H_ + nt*2 + hh)*C_ + (mt & 15)*4 + ch] = u;
    }
  }
  __syncthreads();

  if (l16 & 1) {
    // W aggregates straight from acc registers (odd lanes hold the v columns).
    // Wv[nh][i-half -> chunk][jl]; rows of subtile i live in chunk wr*2 + (i>=4).
    float Wv[2][2][2] = {};
#pragma unroll
    for (int nh = 0; nh < 2; ++nh)
#pragma unroll
      for (int i = 0; i < 8; ++i)
#pragma unroll
        for (int r = 0; r < 4; ++r) {
          const int t = wr*128 + i*16 + quad*4 + r;
          const float p = pS[nh*256 + t];
          Wv[nh][i>>2][0] += p * fmaxf(acc[i][nh*2+0][r], 0.f);
          Wv[nh][i>>2][1] += p * fmaxf(acc[i][nh*2+1][r], 0.f);
        }
#pragma unroll
    for (int nh = 0; nh < 2; ++nh)
#pragma unroll
      for (int c2 = 0; c2 < 2; ++c2)
#pragma unroll
        for (int jl = 0; jl < 2; ++jl) {
          float w = Wv[nh][c2][jl];
          w += __shfl_xor(w, 16);     // reduce across quads (rows of each subtile)
          w += __shfl_xor(w, 32);
          if (quad == 0) {
            const int blk = (b*H_ + nt*2 + nh)*C_ + (mt & 15)*4 + wr*2 + c2;
            aggW[(size_t)blk * D_ + wc*16 + jl*8 + (l16 >> 1)] = w;
          }
        }
  }
  {
    // coalesced v store: 512 rows x 128 B (vbuf flat [bh][t][d])
    const int rr = tid >> 3;          // 0..63
    const int d0 = (tid & 7) * 8;
#pragma unroll
    for (int k2 = 0; k2 < 8; ++k2) {
      const int row = rr + 64*k2;     // 0..511
      const int hh  = row >> 8;
      const int t   = row & 255;
      uint4 val = *(const uint4*)&vtile[(hh*256 + t)*72 + d0];
      *(uint4*)&vbuf[((size_t)(b*H_ + nt*2 + hh) * T_ + t0 + t) * D_ + d0] = val;
    }
  }
}

// ---------------- pass 3: additive prefix + seeded scan + h-reduction (R2 form) --------
__global__ __launch_bounds__(1024)
void scan_pass3(const u16* __restrict__ vbuf, const float* __restrict__ pbuf,
                const float* __restrict__ aggU, const float* __restrict__ aggW,
                float* __restrict__ out) {
  __shared__ float pS[H_][CL_];         // 4 KB
  __shared__ float wbuf[H_][8][D_ + 1]; // 33.3 KB
  int bc = blockIdx.x;
  int b  = bc >> 6;
  int c  = bc & (C_ - 1);
  int tid  = threadIdx.x;
  int h    = tid >> 6;
  int lane = tid & 63;
  int bh   = b * H_ + h;
  int t0   = c * CL_;

  pS[h][lane] = pbuf[(size_t)bh * T_ + t0 + lane];

  // additive exclusive prefix over chunks [0,c): independent loads, pipelines freely
  float U = 0.f, W = 0.f;
  for (int j = 0; j < c; ++j) {
    int idx = bh * C_ + j;
    U += aggU[idx];
    W += aggW[(size_t)idx * D_ + lane];
  }
  __syncthreads();

  const u16* vp = vbuf + ((size_t)bh * T_ + t0) * D_ + lane;
  for (int gg = 0; gg < 8; ++gg) {
#pragma unroll
    for (int ii = 0; ii < 8; ++ii) {
      int i = gg * 8 + ii;
      float p = pS[h][i];
      float v = bf2f(vp[i * D_]);
      U += p;
      W += p * v;
      wbuf[h][ii][lane] = __fdividef(W, U);
    }
    __syncthreads();
    if (tid < 512) {
      int ii = tid >> 6, dd = tid & 63;
      float acc = 0.f;
#pragma unroll
      for (int hh = 0; hh < H_; ++hh) acc += wbuf[hh][ii][dd];
      out[((size_t)b * T_ + t0 + gg*8 + ii) * D_ + dd] = acc;
    }
    __syncthreads();
  }
}

extern "C" void kernel_launch(void* const* d_in, const int* in_sizes, int n_in,
                              void* d_out, int out_size, void* d_ws, size_t ws_size,
                              hipStream_t stream) {
  const float* inputs = (const float*)d_in[0];   // (B,T,DIN)
  const float* kvk    = (const float*)d_in[1];   // (DIN,H,D,2)
  const float* qk     = (const float*)d_in[2];   // (H,D)
  float* out = (float*)d_out;
  char* ws = (char*)d_ws;

  u16*   aB   = (u16*)ws;                       // 33,554,432 B  inputs bf16 [M][K]
  u16*   wBt  = (u16*)(ws + 33554432);          //  4,194,304 B  weights bf16 [N][K]
  u16*   vb   = (u16*)(ws + 37748736);          // 33,554,432 B  v bf16 [b,h,t,d]
  float* pb   = (float*)(ws + 71303168);        //  1,048,576 B  p=exp(s) [b,h,t]
  float* aggU = (float*)(ws + 72351744);        //     16,384 B
  float* aggW = (float*)(ws + 72368128);        //  1,048,576 B  (ends ~73.4 MB)

  prep<<<10240, 256, 0, stream>>>(inputs, kvk, aB, wBt);
  gemm_kv<<<2048 / 4, 512, 131072, stream>>>(aB, wBt, qk, pb, vb, aggU, aggW);
  scan_pass3<<<B_*C_, 1024, 0, stream>>>(vb, pb, aggU, aggW, out);
}

// Round 5
// 204.042 us; speedup vs baseline: 1.0068x; 1.0068x over previous
//
#include <hip/hip_runtime.h>
#include <hip/hip_bf16.h>
#include <math.h>

#define B_   4
#define T_   4096
#define DIN_ 1024
#define H_   16
#define D_   64
#define M_   (B_*T_)      // 16384
#define N_   (H_*D_*2)    // 2048
#define K_   DIN_         // 1024
#define C_   64           // scan chunks per (b,h) chain
#define CL_  (T_/C_)      // 64 steps per chunk

typedef unsigned short u16;
typedef __attribute__((ext_vector_type(8))) short short8_t;
typedef __attribute__((ext_vector_type(4))) float float4_t;

__device__ __forceinline__ u16 f2bf(float f) {
  unsigned int x = __float_as_uint(f);
  x += 0x7fffu + ((x >> 16) & 1u);   // round-to-nearest-even (finite inputs)
  return (u16)(x >> 16);
}
__device__ __forceinline__ float bf2f(unsigned int u) {
  return __uint_as_float((u & 0xffffu) << 16);
}
__device__ __forceinline__ unsigned pk_bf16(float x, float y) {
  float2 f; f.x = x; f.y = y;
  union { __hip_bfloat162 h2; unsigned u; } c;
  c.h2 = __float22bfloat162_rn(f);
  return c.u;
}

// async global->LDS, 16 B per lane. LDS dest = wave-uniform base + lane*16.
__device__ __forceinline__ void g2l16(const u16* g, u16* l) {
  __builtin_amdgcn_global_load_lds(
      (const __attribute__((address_space(1))) void*)g,
      (__attribute__((address_space(3))) void*)l, 16, 0, 0);
}

// ---------------- prep: cast inputs + cast-transpose weights (unchanged) ----------------
__global__ __launch_bounds__(256)
void prep(const float* __restrict__ inputs, const float* __restrict__ kvk,
          u16* __restrict__ aB, u16* __restrict__ wBt) {
  __shared__ float tile[32][33];
  int bid = blockIdx.x;
  int tid = threadIdx.x;
  if (bid < 8192) {
    int i = bid * 256 + tid;          // over M*K/8
    const float4* src = (const float4*)inputs;
    float4 a = src[2*i], b = src[2*i+1];
    uint4 o;
    o.x = pk_bf16(a.x, a.y);
    o.y = pk_bf16(a.z, a.w);
    o.z = pk_bf16(b.x, b.y);
    o.w = pk_bf16(b.z, b.w);
    ((uint4*)aB)[i] = o;
  } else {
    int b2 = bid - 8192;              // 2048 blocks
    int kb = (b2 & 31) * 32;          // K/32 = 32
    int nb = (b2 >> 5) * 32;          // N/32 = 64
    int r  = tid >> 3;                // 0..31
    int c4 = (tid & 7) * 4;           // 0..28
    float4 v = *(const float4*)&kvk[(size_t)(kb + r) * N_ + nb + c4];
    tile[r][c4+0] = v.x; tile[r][c4+1] = v.y; tile[r][c4+2] = v.z; tile[r][c4+3] = v.w;
    __syncthreads();
    uint2 o;
    o.x = pk_bf16(tile[c4+0][r], tile[c4+1][r]);
    o.y = pk_bf16(tile[c4+2][r], tile[c4+3][r]);
    *(uint2*)&wBt[(size_t)(nb + r) * K_ + kb + c4] = o;
  }
}

// ---------------- gemm_kv R5: 256x256 tile, 16 waves, BK=32, TRIPLE-buffered ------------
// 1024 thr = 16 waves (4x4), wave tile 64x64. LDS 96 KB:
//   A[par 3][256 rows][32 u16]  @ par*8192 u16   (16 KB per parity)
//   B[par 3][256 rows][32 u16]  @ 24576 + par*8192 u16
// Row = 32 u16 (64 B), granule = 8 u16 (16 B); swizzle g' = g ^ ((row>>1)&3)
// (max 2-way bank aliasing = free), pre-XOR'd on the global source.
// Phase (= one K-tile, BK=32), ALL phases identical:
//   8 ds_read_b128 (4 A-frags + 4 B-frags, par kt%3)
//   2 g2l16        (stage K-tile kt+2 into par (kt+2)%3  -- never the read par!)
//   barrier; 16 MFMA (setprio); s_waitcnt vmcnt(2); barrier
// vmcnt(2) leaves this phase's own 2 stage-loads in flight and guarantees
// kt+1's stages (issued last phase) landed. Counted wait every phase, no
// drain-0 until the 2-phase tail. 32 phases, 64 barriers/block.

#define FENCE asm volatile("" ::: "memory")
#define KBAR do { FENCE; __builtin_amdgcn_s_barrier(); FENCE; } while (0)

#define READS(PAR) do { _Pragma("unroll") \
  for (int i_ = 0; i_ < 4; ++i_) \
    af[i_] = *(const short8_t*)&lds[(PAR)*8192 + aBase + i_*512]; \
  _Pragma("unroll") \
  for (int j_ = 0; j_ < 4; ++j_) \
    bfq[j_] = *(const short8_t*)&lds[(PAR)*8192 + bBase + j_*512]; \
} while (0)

#define MFMAS do { \
  __builtin_amdgcn_s_setprio(1); \
  _Pragma("unroll") for (int i_ = 0; i_ < 4; ++i_) \
  _Pragma("unroll") for (int j_ = 0; j_ < 4; ++j_) \
    acc[i_][j_] = __builtin_amdgcn_mfma_f32_16x16x32_bf16( \
        af[i_], bfq[j_], acc[i_][j_], 0, 0, 0); \
  __builtin_amdgcn_s_setprio(0); \
} while (0)

#define PHASE(PAR, PAR2, KT) do { \
  short8_t af[4], bfq[4]; \
  READS(PAR); \
  g2l16(gA + ((KT)+2)*32, lds +         (PAR2)*8192 + wv*512); \
  g2l16(gB + ((KT)+2)*32, lds + 24576 + (PAR2)*8192 + wv*512); \
  KBAR; \
  MFMAS; \
  asm volatile("s_waitcnt vmcnt(2)" ::: "memory"); \
  KBAR; \
} while (0)

__global__ __launch_bounds__(1024)
void gemm_kv(const u16* __restrict__ A, const u16* __restrict__ Bt,
             const float* __restrict__ q,
             float* __restrict__ pbuf, u16* __restrict__ vbuf,
             float* __restrict__ aggU, float* __restrict__ aggW) {
  extern __shared__ __align__(16) char smem[];
  u16* lds = (u16*)smem;

  const int tid  = threadIdx.x;
  const int wv   = tid >> 6;          // 0..15
  const int lane = tid & 63;
  const int quad = lane >> 4;
  const int l16  = lane & 15;
  const int wr2  = wv >> 2;           // 0..3  (m: 64-row group)
  const int wc2  = wv & 3;            // 0..3  (n: 64-col group)

  // XCD-aware bijective swizzle (512 % 8 == 0)
  const int g  = blockIdx.x;
  const int wg = (g & 7) * 64 + (g >> 3);
  const int nt = wg & 7;              // heads {2nt, 2nt+1}
  const int mt = wg >> 3;             // rows [mt*256, +256)
  const int bm = mt * 256;
  const int bn = nt * 256;

  // staging: thread -> (row = tid>>2, granule = tid&3), global src pre-XOR'd
  const u16* gA = A  + (size_t)(bm + (tid >> 2)) * K_ + (((tid & 3) ^ ((tid >> 3) & 3)) * 8);
  const u16* gB = Bt + (size_t)(bn + (tid >> 2)) * K_ + (((tid & 3) ^ ((tid >> 3) & 3)) * 8);

  // fragment ds_read bases (u16): row = {wr2|wc2}*64 + frag*16 + l16, stride 32
  const int sg    = (quad ^ ((l16 >> 1) & 3)) * 8;   // swizzled granule
  const int aBase = wr2 * 2048 + l16 * 32 + sg;            // + par*8192 + i*512
  const int bBase = 24576 + wc2 * 2048 + l16 * 32 + sg;    // + par*8192 + j*512

  float4_t acc[4][4] = {};

  // prologue: stage kt0, kt1; verify kt0; barrier
  g2l16(gA,      lds +                 wv*512);
  g2l16(gB,      lds + 24576 +         wv*512);
  g2l16(gA + 32, lds +          8192 + wv*512);
  g2l16(gB + 32, lds + 24576 +  8192 + wv*512);
  asm volatile("s_waitcnt vmcnt(2)" ::: "memory");
  KBAR;

  // main loop: kt = 0..29 (kt+2 <= 31 always stages)
#pragma unroll 1
  for (int kq = 0; kq < 10; ++kq) {
    const int kt = kq * 3;
    PHASE(0, 2, kt + 0);
    PHASE(1, 0, kt + 1);
    PHASE(2, 1, kt + 2);
  }
  // tail kt=30 (par 0): no stage; drain
  {
    short8_t af[4], bfq[4];
    READS(0);
    KBAR;
    MFMAS;
    asm volatile("s_waitcnt vmcnt(0)" ::: "memory");
    KBAR;
  }
  // tail kt=31 (par 1): everything resident
  {
    short8_t af[4], bfq[4];
    READS(1);
    KBAR;
    MFMAS;
    KBAR;
  }

  // ---------------- fused epilogue (R5, 16-wave mapping) ----------------
  // C/D frag: col(n) = l16, row(m) = quad*4 + reg.
  // t = wr2*64 + i*16 + quad*4 + r;  n' = wc2*64 + j*16 + l16.
  // head-local nh = wc2>>1; col-half wc2p = wc2&1. parity(n') = parity(l16):
  // odd -> v column d = wc2p*32 + j*8 + (l16>>1); even -> k column (dot with q).
  u16*   vtile = (u16*)smem;                  // [2][256][72] u16 = 73728 B
  float* sred  = (float*)(smem + 73728);      // [2][256][5]  f32 = 10240 B
  float* pS    = (float*)(smem + 83968);      // [2][256]     f32 =  2048 B (end 86016)

  const int nh   = wc2 >> 1;
  const int wc2p = wc2 & 1;
  const int hd   = l16 >> 1;

  float qv[4];
#pragma unroll
  for (int j = 0; j < 4; ++j)
    qv[j] = q[(nt*2 + nh)*64 + wc2p*32 + j*8 + hd];

#pragma unroll
  for (int i = 0; i < 4; ++i) {
#pragma unroll
    for (int r = 0; r < 4; ++r) {
      const int t = wr2*64 + i*16 + quad*4 + r;
      float x0 = fmaxf(acc[i][0][r], 0.f);
      float x1 = fmaxf(acc[i][1][r], 0.f);
      float x2 = fmaxf(acc[i][2][r], 0.f);
      float x3 = fmaxf(acc[i][3][r], 0.f);
      if (l16 & 1) {               // v columns -> staged transpose
        vtile[(nh*256 + t)*72 + wc2p*32 +  0 + hd] = f2bf(x0);
        vtile[(nh*256 + t)*72 + wc2p*32 +  8 + hd] = f2bf(x1);
        vtile[(nh*256 + t)*72 + wc2p*32 + 16 + hd] = f2bf(x2);
        vtile[(nh*256 + t)*72 + wc2p*32 + 24 + hd] = f2bf(x3);
      } else {                     // k columns: q-dot partials
        float ps = qv[0]*x0 + qv[1]*x1 + qv[2]*x2 + qv[3]*x3;
        ps += __shfl_xor(ps, 2);
        ps += __shfl_xor(ps, 4);
        if ((l16 & 7) == 0)
          sred[(nh*256 + t)*5 + wc2p*2 + (l16 >> 3)] = ps;
      }
    }
  }
  __syncthreads();

  const int b  = mt >> 4;             // 16 m-tiles per batch
  const int t0 = (mt & 15) * 256;
  if (tid < 512) {
    // p-phase: wave = one (hh, 64-t chunk); U via shuffle reduce
    const int hh = tid >> 8;
    const int t  = tid & 255;
    const float* sr = &sred[(hh*256 + t)*5];
    float s = sr[0] + sr[1] + sr[2] + sr[3];
    float p = __expf(fminf(fmaxf(s, -60.f), 60.f));
    pS[hh*256 + t] = p;
    pbuf[(size_t)(b*H_ + nt*2 + hh) * T_ + t0 + t] = p;
    float u = p;
#pragma unroll
    for (int off = 32; off; off >>= 1) u += __shfl_down(u, off);
    if (lane == 0)
      aggU[(b*H_ + nt*2 + hh)*C_ + (mt & 15)*4 + ((tid >> 6) & 3)] = u;
  }
  __syncthreads();

  if (l16 & 1) {
    // W aggregates straight from acc (odd lanes hold v columns); wave's t-range
    // is exactly one 64-t chunk (wr2), one head (nh), one col-half (wc2p).
    float Wv[4] = {};
#pragma unroll
    for (int i = 0; i < 4; ++i)
#pragma unroll
      for (int r = 0; r < 4; ++r) {
        const int t = wr2*64 + i*16 + quad*4 + r;
        const float p = pS[nh*256 + t];
        Wv[0] += p * fmaxf(acc[i][0][r], 0.f);
        Wv[1] += p * fmaxf(acc[i][1][r], 0.f);
        Wv[2] += p * fmaxf(acc[i][2][r], 0.f);
        Wv[3] += p * fmaxf(acc[i][3][r], 0.f);
      }
#pragma unroll
    for (int j = 0; j < 4; ++j) {
      float w = Wv[j];
      w += __shfl_xor(w, 16);       // reduce across quads (t within chunk)
      w += __shfl_xor(w, 32);
      if (quad == 0) {
        const int blk = (b*H_ + nt*2 + nh)*C_ + (mt & 15)*4 + wr2;
        aggW[(size_t)blk * D_ + wc2p*32 + j*8 + hd] = w;
      }
    }
  }
  {
    // coalesced v store: 512 rows x 128 B (vbuf flat [bh][t][d])
    const int d0 = (tid & 7) * 8;
#pragma unroll
    for (int k2 = 0; k2 < 4; ++k2) {
      const int row = (tid >> 3) + 128*k2;   // 0..511
      const int hh  = row >> 8;
      const int t   = row & 255;
      uint4 val = *(const uint4*)&vtile[(hh*256 + t)*72 + d0];
      *(uint4*)&vbuf[((size_t)(b*H_ + nt*2 + hh) * T_ + t0 + t) * D_ + d0] = val;
    }
  }
}

// ---------------- pass 3: additive prefix + seeded scan + h-reduction (unchanged) ------
__global__ __launch_bounds__(1024)
void scan_pass3(const u16* __restrict__ vbuf, const float* __restrict__ pbuf,
                const float* __restrict__ aggU, const float* __restrict__ aggW,
                float* __restrict__ out) {
  __shared__ float pS[H_][CL_];         // 4 KB
  __shared__ float wbuf[H_][8][D_ + 1]; // 33.3 KB
  int bc = blockIdx.x;
  int b  = bc >> 6;
  int c  = bc & (C_ - 1);
  int tid  = threadIdx.x;
  int h    = tid >> 6;
  int lane = tid & 63;
  int bh   = b * H_ + h;
  int t0   = c * CL_;

  pS[h][lane] = pbuf[(size_t)bh * T_ + t0 + lane];

  // additive exclusive prefix over chunks [0,c): independent loads, pipelines freely
  float U = 0.f, W = 0.f;
  for (int j = 0; j < c; ++j) {
    int idx = bh * C_ + j;
    U += aggU[idx];
    W += aggW[(size_t)idx * D_ + lane];
  }
  __syncthreads();

  const u16* vp = vbuf + ((size_t)bh * T_ + t0) * D_ + lane;
  for (int gg = 0; gg < 8; ++gg) {
#pragma unroll
    for (int ii = 0; ii < 8; ++ii) {
      int i = gg * 8 + ii;
      float p = pS[h][i];
      float v = bf2f(vp[i * D_]);
      U += p;
      W += p * v;
      wbuf[h][ii][lane] = __fdividef(W, U);
    }
    __syncthreads();
    if (tid < 512) {
      int ii = tid >> 6, dd = tid & 63;
      float acc = 0.f;
#pragma unroll
      for (int hh = 0; hh < H_; ++hh) acc += wbuf[hh][ii][dd];
      out[((size_t)b * T_ + t0 + gg*8 + ii) * D_ + dd] = acc;
    }
    __syncthreads();
  }
}

extern "C" void kernel_launch(void* const* d_in, const int* in_sizes, int n_in,
                              void* d_out, int out_size, void* d_ws, size_t ws_size,
                              hipStream_t stream) {
  const float* inputs = (const float*)d_in[0];   // (B,T,DIN)
  const float* kvk    = (const float*)d_in[1];   // (DIN,H,D,2)
  const float* qk     = (const float*)d_in[2];   // (H,D)
  float* out = (float*)d_out;
  char* ws = (char*)d_ws;

  u16*   aB   = (u16*)ws;                       // 33,554,432 B  inputs bf16 [M][K]
  u16*   wBt  = (u16*)(ws + 33554432);          //  4,194,304 B  weights bf16 [N][K]
  u16*   vb   = (u16*)(ws + 37748736);          // 33,554,432 B  v bf16 [b,h,t,d]
  float* pb   = (float*)(ws + 71303168);        //  1,048,576 B  p=exp(s) [b,h,t]
  float* aggU = (float*)(ws + 72351744);        //     16,384 B
  float* aggW = (float*)(ws + 72368128);        //  1,048,576 B  (ends ~73.4 MB)

  prep<<<10240, 256, 0, stream>>>(inputs, kvk, aB, wBt);
  gemm_kv<<<512, 1024, 98304, stream>>>(aB, wBt, qk, pb, vb, aggU, aggW);
  scan_pass3<<<B_*C_, 1024, 0, stream>>>(vb, pb, aggU, aggW, out);
}